// Round 4
// baseline (307.414 us; speedup 1.0000x reference)
//
#include <hip/hip_runtime.h>

typedef _Float16 f16;
typedef _Float16 half8 __attribute__((ext_vector_type(8)));
typedef float floatx4 __attribute__((ext_vector_type(4)));

#define MFMA16(a,b,c) __builtin_amdgcn_mfma_f32_16x16x32_f16((a),(b),(c),0,0,0)
// (1/sqrt(128)) * log2(e)
#define RSL2E 0.12751743f

__device__ __forceinline__ void split2(float x, f16 &h, f16 &l) {
  f16 hh = (f16)x;
  h = hh;
  l = (f16)(x - (float)hh);
}

// ---- LDS staging: rows of 64 halves (128B pitch), XOR-swizzled ----
__device__ __forceinline__ void stage_rows64(const f16* __restrict__ g, int gstride,
                                             f16* lds, int rows, int tid, int nthr) {
  int total = rows * 8;
  for (int idx = tid; idx < total; idx += nthr) {
    int row = idx >> 3, slot = idx & 7;
    float4 v = *(const float4*)(g + (size_t)row * gstride + slot * 8);
    int lofs = ((row << 7) + (slot << 4)) ^ ((row & 7) << 4);
    *(float4*)((char*)lds + lofs) = v;
  }
}
// rows of 128 halves (256B pitch), XOR-swizzled
__device__ __forceinline__ void stage_rows128(const f16* __restrict__ g, int gstride,
                                              f16* lds, int rows, int tid, int nthr) {
  int total = rows * 16;
  for (int idx = tid; idx < total; idx += nthr) {
    int row = idx >> 4, slot = idx & 15;
    float4 v = *(const float4*)(g + (size_t)row * gstride + slot * 8);
    int lofs = ((row << 8) + (slot << 4)) ^ ((row & 7) << 4);
    *(float4*)((char*)lds + lofs) = v;
  }
}
__device__ __forceinline__ half8 fragP128(const f16* lds, int row, int kofs) {
  int ofs = ((row << 7) + (kofs << 1)) ^ ((row & 7) << 4);
  return *(const half8*)((const char*)lds + ofs);
}
__device__ __forceinline__ half8 fragP256(const f16* lds, int row, int kofs) {
  int ofs = ((row << 8) + (kofs << 1)) ^ ((row & 7) << 4);
  return *(const half8*)((const char*)lds + ofs);
}

// ---- split fp32 -> (h,l) f16 pairs, elementwise ----
__global__ void k_split(const float4* __restrict__ in, uint2* __restrict__ outh,
                        uint2* __restrict__ outl, int n4) {
  int stride = gridDim.x * blockDim.x;
  for (int i = blockIdx.x * blockDim.x + threadIdx.x; i < n4; i += stride) {
    float4 v = in[i];
    union { f16 a[4]; uint2 u; } ph, pl;
    split2(v.x, ph.a[0], pl.a[0]);
    split2(v.y, ph.a[1], pl.a[1]);
    split2(v.z, ph.a[2], pl.a[2]);
    split2(v.w, ph.a[3], pl.a[3]);
    outh[i] = ph.u;
    outl[i] = pl.u;
  }
}

// ---- transpose + split the three weight matrices ----
__global__ void k_splitW(const float* __restrict__ Wq, const float* __restrict__ Wkv,
                         const float* __restrict__ Wo,
                         f16* WqTh, f16* WqTl, f16* WkvTh, f16* WkvTl,
                         f16* WoTh, f16* WoTl) {
  int idx = blockIdx.x * 256 + threadIdx.x;
  if (idx >= 65536) return;
  float v; f16 *ph, *pl; int dst;
  if (idx < 16384) {
    int n = idx >> 7, c = idx & 127;
    v = Wq[c * 128 + n]; ph = WqTh; pl = WqTl; dst = idx;
  } else if (idx < 49152) {
    int t = idx - 16384; int n = t >> 7, c = t & 127;
    v = Wkv[c * 256 + n]; ph = WkvTh; pl = WkvTl; dst = t;
  } else {
    int t = idx - 49152; int n = t >> 7, c = t & 127;
    v = Wo[c * 128 + n]; ph = WoTh; pl = WoTl; dst = t;
  }
  f16 h, l; split2(v, h, l);
  ph[dst] = h; pl[dst] = l;
}

// ---- split-f16 GEMM: out[64 rows][128 cols] = A[64][128] * BT[128][128]^T + bias ----
// Output is SINGLE f16 (rounded once). mode 0: row-major [l][c]; mode 1: transposed vT [b][c][l]
__global__ __launch_bounds__(512, 2)
void k_proj(const f16* __restrict__ Ah, const f16* __restrict__ Al,
            const f16* __restrict__ BTh, const f16* __restrict__ BTl,
            const float* __restrict__ bias,
            f16* __restrict__ out, int mode) {
  __shared__ f16 pool[24576];
  f16* sAh = pool;           // [64][64]
  f16* sAl = pool + 4096;
  f16* sBh = pool + 8192;    // [128][64]
  f16* sBl = pool + 16384;
  int tid = threadIdx.x, wave = tid >> 6, lane = tid & 63, lg = lane >> 4, lr = lane & 15;
  int wm = wave >> 2, wn = wave & 3;   // 2 x 4 waves, 32x32 wave tiles
  size_t rowbase = (size_t)blockIdx.x * 64;
  floatx4 zero = {0.f, 0.f, 0.f, 0.f};
  floatx4 acc[2][2] = {{zero, zero}, {zero, zero}};
  for (int cc = 0; cc < 128; cc += 64) {
    __syncthreads();
    stage_rows64(Ah + rowbase * 128 + cc, 128, sAh, 64, tid, 512);
    stage_rows64(Al + rowbase * 128 + cc, 128, sAl, 64, tid, 512);
    stage_rows64(BTh + cc, 128, sBh, 128, tid, 512);
    stage_rows64(BTl + cc, 128, sBl, 128, tid, 512);
    __syncthreads();
    for (int kc = 0; kc < 64; kc += 32) {
      half8 ah[2], al[2];
      for (int fm = 0; fm < 2; fm++) {
        ah[fm] = fragP128(sAh, wm * 32 + fm * 16 + lr, kc + lg * 8);
        al[fm] = fragP128(sAl, wm * 32 + fm * 16 + lr, kc + lg * 8);
      }
      for (int fn = 0; fn < 2; fn++) {
        half8 bh = fragP128(sBh, wn * 32 + fn * 16 + lr, kc + lg * 8);
        half8 bl = fragP128(sBl, wn * 32 + fn * 16 + lr, kc + lg * 8);
        for (int fm = 0; fm < 2; fm++) {
          acc[fm][fn] = MFMA16(ah[fm], bh, acc[fm][fn]);
          acc[fm][fn] = MFMA16(ah[fm], bl, acc[fm][fn]);
          acc[fm][fn] = MFMA16(al[fm], bh, acc[fm][fn]);
        }
      }
    }
  }
  __syncthreads();
  f16* e = pool;          // [64][136] padded, single
  for (int fm = 0; fm < 2; fm++) for (int fn = 0; fn < 2; fn++) {
    int n = wn * 32 + fn * 16 + lr;
    float bs = bias[n];
    for (int jj = 0; jj < 4; jj++) {
      int m = wm * 32 + fm * 16 + lg * 4 + jj;
      e[m * 136 + n] = (f16)(acc[fm][fn][jj] + bs);
    }
  }
  __syncthreads();
  if (mode == 0) {
    for (int idx = tid; idx < 1024; idx += 512) {
      int r = idx >> 4, sl = idx & 15;
      *(float4*)(out + (rowbase + r) * 128 + sl * 8) =
          *(const float4*)((const char*)e + r * 272 + sl * 16);
    }
  } else {
    size_t bidx = rowbase >> 13, lofs = rowbase & 8191;
    for (int idx = tid; idx < 1024; idx += 512) {
      int c = idx >> 3, sl = idx & 7;
      union { f16 a[8]; float4 v; } th;
      for (int t = 0; t < 8; t++) th.a[t] = e[(sl * 8 + t) * 136 + c];
      *(float4*)(out + (bidx * 128 + c) * 8192 + lofs + sl * 8) = th.v;
    }
  }
}

// ---- final projection: out fp32 = attnout(split) * WoT^T + bo ----
__global__ __launch_bounds__(512, 2)
void k_final(const f16* __restrict__ Ah, const f16* __restrict__ Al,
             const f16* __restrict__ BTh, const f16* __restrict__ BTl,
             const float* __restrict__ bias, float* __restrict__ out) {
  __shared__ f16 pool[24576];
  f16* sAh = pool;
  f16* sAl = pool + 4096;
  f16* sBh = pool + 8192;
  f16* sBl = pool + 16384;
  int tid = threadIdx.x, wave = tid >> 6, lane = tid & 63, lg = lane >> 4, lr = lane & 15;
  int wm = wave >> 2, wn = wave & 3;
  size_t rowbase = (size_t)blockIdx.x * 64;
  floatx4 zero = {0.f, 0.f, 0.f, 0.f};
  floatx4 acc[2][2] = {{zero, zero}, {zero, zero}};
  for (int cc = 0; cc < 128; cc += 64) {
    __syncthreads();
    stage_rows64(Ah + rowbase * 128 + cc, 128, sAh, 64, tid, 512);
    stage_rows64(Al + rowbase * 128 + cc, 128, sAl, 64, tid, 512);
    stage_rows64(BTh + cc, 128, sBh, 128, tid, 512);
    stage_rows64(BTl + cc, 128, sBl, 128, tid, 512);
    __syncthreads();
    for (int kc = 0; kc < 64; kc += 32) {
      half8 ah[2], al[2];
      for (int fm = 0; fm < 2; fm++) {
        ah[fm] = fragP128(sAh, wm * 32 + fm * 16 + lr, kc + lg * 8);
        al[fm] = fragP128(sAl, wm * 32 + fm * 16 + lr, kc + lg * 8);
      }
      for (int fn = 0; fn < 2; fn++) {
        half8 bh = fragP128(sBh, wn * 32 + fn * 16 + lr, kc + lg * 8);
        half8 bl = fragP128(sBl, wn * 32 + fn * 16 + lr, kc + lg * 8);
        for (int fm = 0; fm < 2; fm++) {
          acc[fm][fn] = MFMA16(ah[fm], bh, acc[fm][fn]);
          acc[fm][fn] = MFMA16(ah[fm], bl, acc[fm][fn]);
          acc[fm][fn] = MFMA16(al[fm], bh, acc[fm][fn]);
        }
      }
    }
  }
  __syncthreads();
  float* ef = (float*)pool;   // [64][132] padded fp32
  for (int fm = 0; fm < 2; fm++) for (int fn = 0; fn < 2; fn++) {
    int n = wn * 32 + fn * 16 + lr;
    float bs = bias[n];
    for (int jj = 0; jj < 4; jj++) {
      int m = wm * 32 + fm * 16 + lg * 4 + jj;
      ef[m * 132 + n] = acc[fm][fn][jj] + bs;
    }
  }
  __syncthreads();
  for (int idx = tid; idx < 2048; idx += 512) {
    int r = idx >> 5, sl = idx & 31;
    *(float4*)(out + (rowbase + r) * 128 + sl * 4) = *(const float4*)(ef + r * 132 + sl * 4);
  }
}

// ---- U[b][i][c] = (1/512) * sum over disallowed k-blocks of their column sums of v ----
__global__ void k_U(const f16* __restrict__ vT, float* __restrict__ U) {
  int b = blockIdx.x >> 7, c = blockIdx.x & 127;
  int tid = threadIdx.x;
  const f16* r = vT + ((size_t)b * 128 + c) * 8192;
  float s = 0.f;
  const float4* r4 = (const float4*)(r + tid * 32);
  for (int t = 0; t < 4; t++) {
    float4 v = r4[t];
    const f16* a = (const f16*)&v;
    for (int u = 0; u < 8; u++) s += (float)a[u];
  }
  __shared__ float part[256];
  __shared__ float bs[16];
  part[tid] = s;
  __syncthreads();
  if (tid < 16) {
    float t = 0.f;
    for (int u = 0; u < 16; u++) t += part[tid * 16 + u];
    bs[tid] = t;
  }
  __syncthreads();
  if (tid < 16) {
    int i = tid;
    float tot = 0.f;
    for (int j = 0; j < 16; j++) tot += bs[j];
    int j0 = i - 2 < 0 ? 0 : i - 2;
    int j1 = i + 2 > 15 ? 15 : i + 2;
    float win = 0.f;
    for (int j = j0; j <= j1; j++) win += bs[j];
    U[((size_t)b * 16 + i) * 128 + c] = (tot - win) * (1.0f / 512.0f);
  }
}

// ---- pass A: Z[b][i][j][d] = sum_s exp2(RSL2E * (k_d . q_s)), single f16 inputs ----
__global__ __launch_bounds__(512, 4)
void k_passA(const f16* __restrict__ kp, const f16* __restrict__ qp,
             float* __restrict__ Z) {
  int bid = blockIdx.x;
  int wg = (bid & 7) * 80 + (bid >> 3);     // XCD-aware bijective swizzle (640 = 8*80)
  int dchunk = wg & 3; int rest = wg >> 2;
  int slot = rest % 5; int rest2 = rest / 5;
  int i = rest2 & 15; int b = rest2 >> 4;
  int j = i - 2 + slot;
  if (j < 0 || j > 15) return;
  __shared__ f16 sK[16384], sQ[16384];  // 64 KiB -> 2 WG/CU
  int tid = threadIdx.x, wave = tid >> 6, lane = tid & 63, lg = lane >> 4, lr = lane & 15;
  int wm = wave >> 1, wn = wave & 1;   // 4 x 2 waves; wave tile 32(d) x 64(s)
  size_t krow = (size_t)b * 8192 + j * 512 + dchunk * 128;
  stage_rows128(kp + krow * 128, 128, sK, 128, tid, 512);
  float zp[2][4] = {{0.f,0.f,0.f,0.f},{0.f,0.f,0.f,0.f}};
  floatx4 zero = {0.f, 0.f, 0.f, 0.f};
  for (int sc = 0; sc < 4; sc++) {
    __syncthreads();
    size_t qrow = (size_t)b * 8192 + i * 512 + sc * 128;
    stage_rows128(qp + qrow * 128, 128, sQ, 128, tid, 512);
    __syncthreads();
    floatx4 acc[2][4] = {{zero,zero,zero,zero},{zero,zero,zero,zero}};
    for (int kc = 0; kc < 128; kc += 32) {
      half8 ah[2];
      for (int fm = 0; fm < 2; fm++)
        ah[fm] = fragP256(sK, wm * 32 + fm * 16 + lr, kc + lg * 8);
      for (int fn = 0; fn < 4; fn++) {
        half8 bh = fragP256(sQ, wn * 64 + fn * 16 + lr, kc + lg * 8);
        for (int fm = 0; fm < 2; fm++)
          acc[fm][fn] = MFMA16(ah[fm], bh, acc[fm][fn]);
      }
    }
    for (int fm = 0; fm < 2; fm++) for (int fn = 0; fn < 4; fn++)
      for (int jj = 0; jj < 4; jj++)
        zp[fm][jj] += exp2f(acc[fm][fn][jj] * RSL2E);
  }
  // in-wave butterfly over lr (16 s-columns)
  for (int off = 1; off < 16; off <<= 1)
    for (int fm = 0; fm < 2; fm++) for (int jj = 0; jj < 4; jj++)
      zp[fm][jj] += __shfl_xor(zp[fm][jj], off, 64);
  // cross-wave combine of the two wn halves via LDS
  __syncthreads();
  float* sred = (float*)sQ;      // 256 floats
  if (lr == 0) {
    for (int fm = 0; fm < 2; fm++) for (int jj = 0; jj < 4; jj++) {
      int d = wm * 32 + fm * 16 + lg * 4 + jj;
      sred[wn * 128 + d] = zp[fm][jj];
    }
  }
  __syncthreads();
  if (tid < 128) {
    size_t zb = (((size_t)(b * 16 + i) * 16 + j) * 512) + dchunk * 128;
    Z[zb + tid] = sred[tid] + sred[128 + tid];
  }
}

// ---- pass B: per (b, i, s-tile of 64, d-half of 256): partial PV into Pbuf (f32) ----
// single-f16 operands; 40 KB LDS -> 4 WG/CU
__global__ __launch_bounds__(512, 8)
void k_passB(const f16* __restrict__ qp, const f16* __restrict__ kp,
             const f16* __restrict__ vT,
             const float* __restrict__ Z, float* __restrict__ Pbuf) {
  int bid = blockIdx.x;
  int wg = ((bid & 7) << 6) | (bid >> 3);   // XCD-aware bijective swizzle (512 = 8*64)
  int dhalf = wg & 1, st = (wg >> 1) & 7, i = (wg >> 4) & 15, b = wg >> 8;
  __shared__ __align__(16) char pool[40960];
  f16* sQ  = (f16*)pool;             // [64 s][128 c], 256B pitch, 16 KB
  f16* sKV = (f16*)(pool + 16384);   // [128][64], 128B pitch, 16 KB (K halves / vT tiles)
  f16* sE  = (f16*)(pool + 32768);   // [64 s][64 d], 128B pitch, 8 KB
  int tid = threadIdx.x, wave = tid >> 6, lane = tid & 63, lg = lane >> 4, lr = lane & 15;
  int w1m = wave >> 1, w1n = wave & 1;    // GEMM1: 4(d) x 2(s)
  int w2m = wave >> 2, w2n = wave & 3;    // GEMM2: 2(s) x 4(c)
  // this thread's K-stage duty (rows krr and krr+64, 16B slot ksl)
  int krr = tid >> 3, ksl = tid & 7;
  int lofsA = ((krr << 7) + (ksl << 4)) ^ ((krr & 7) << 4);
  int lofsB = (((krr + 64) << 7) + (ksl << 4)) ^ ((krr & 7) << 4);
  size_t qrow = (size_t)b * 8192 + i * 512 + st * 64;
  stage_rows128(qp + qrow * 128, 128, sQ, 64, tid, 512);
  floatx4 zero = {0.f, 0.f, 0.f, 0.f};
  floatx4 acc2[2][2] = {{zero, zero}, {zero, zero}};
  for (int slot = 0; slot < 5; slot++) {
    int j = i - 2 + slot;
    if (j < 0 || j > 15) continue;
    for (int dc = 0; dc < 2; dc++) {
      int dchunk = dhalf * 2 + dc;
      const f16* kb = kp + ((size_t)b * 8192 + j * 512 + dchunk * 128) * 128;
      // T14: issue cc=0 loads BEFORE the barrier
      float4 p0a = *(const float4*)(kb + krr * 128 + ksl * 8);
      float4 p0b = *(const float4*)(kb + (krr + 64) * 128 + ksl * 8);
      floatx4 acc1[2][2] = {{zero, zero}, {zero, zero}};
      __syncthreads();                       // prev readers of sKV done
      *(float4*)((char*)sKV + lofsA) = p0a;
      *(float4*)((char*)sKV + lofsB) = p0b;
      // prefetch cc=64 (lands during GEMM1(cc=0))
      float4 p1a = *(const float4*)(kb + krr * 128 + 64 + ksl * 8);
      float4 p1b = *(const float4*)(kb + (krr + 64) * 128 + 64 + ksl * 8);
      __syncthreads();
      for (int kc = 0; kc < 64; kc += 32) {  // GEMM1 over cc=0 half
        half8 ah[2];
        for (int fm = 0; fm < 2; fm++)
          ah[fm] = fragP128(sKV, w1m * 32 + fm * 16 + lr, kc + lg * 8);
        for (int fn = 0; fn < 2; fn++) {
          half8 bh = fragP256(sQ, w1n * 32 + fn * 16 + lr, kc + lg * 8);
          for (int fm = 0; fm < 2; fm++)
            acc1[fm][fn] = MFMA16(ah[fm], bh, acc1[fm][fn]);
        }
      }
      __syncthreads();
      *(float4*)((char*)sKV + lofsA) = p1a;
      *(float4*)((char*)sKV + lofsB) = p1b;
      __syncthreads();
      for (int kc = 0; kc < 64; kc += 32) {  // GEMM1 over cc=64 half
        half8 ah[2];
        for (int fm = 0; fm < 2; fm++)
          ah[fm] = fragP128(sKV, w1m * 32 + fm * 16 + lr, kc + lg * 8);
        for (int fn = 0; fn < 2; fn++) {
          half8 bh = fragP256(sQ, w1n * 32 + fn * 16 + lr, 64 + kc + lg * 8);
          for (int fm = 0; fm < 2; fm++)
            acc1[fm][fn] = MFMA16(ah[fm], bh, acc1[fm][fn]);
        }
      }
      float rz[2][4];
      {
        size_t zb = (((size_t)(b * 16 + i) * 16 + j) * 512) + dchunk * 128;
        for (int fm = 0; fm < 2; fm++) for (int jj = 0; jj < 4; jj++)
          rz[fm][jj] = 1.0f / Z[zb + w1m * 32 + fm * 16 + lg * 4 + jj];
      }
      for (int dsub = 0; dsub < 2; dsub++) {
        __syncthreads();   // prev GEMM2 done with E and KV buffers
        if ((w1m >> 1) == dsub) {
          // this half's waves write E' = exp(S)/Z (single f16)
          for (int fm = 0; fm < 2; fm++) for (int fn = 0; fn < 2; fn++)
            for (int jj = 0; jj < 4; jj++) {
              int dl = w1m * 32 + fm * 16 + lg * 4 + jj;
              int ds = dl - dsub * 64;
              int s = w1n * 32 + fn * 16 + lr;
              float e = exp2f(acc1[fm][fn][jj] * RSL2E) * rz[fm][jj];
              int ofs = ((s << 7) + (ds << 1)) ^ ((s & 7) << 4);
              *(f16*)((char*)sE + ofs) = (f16)e;
            }
        } else {
          // other 4 waves stage vT tile [128 c][64 d]
          int tt = (wave >= 4) ? (tid - 256) : tid;
          size_t vcol = (size_t)j * 512 + dchunk * 128 + dsub * 64;
          const f16* gv = vT + (size_t)b * 128 * 8192 + vcol;
          for (int idx = tt; idx < 1024; idx += 256) {
            int row = idx >> 3, sl = idx & 7;
            int lofs = ((row << 7) + (sl << 4)) ^ ((row & 7) << 4);
            *(float4*)((char*)sKV + lofs) = *(const float4*)(gv + (size_t)row * 8192 + sl * 8);
          }
        }
        __syncthreads();
        for (int kc = 0; kc < 64; kc += 32) {
          half8 ah[2];
          for (int fm = 0; fm < 2; fm++)
            ah[fm] = fragP128(sE, w2m * 32 + fm * 16 + lr, kc + lg * 8);
          for (int fn = 0; fn < 2; fn++) {
            half8 bh = fragP128(sKV, w2n * 32 + fn * 16 + lr, kc + lg * 8);
            for (int fm = 0; fm < 2; fm++)
              acc2[fm][fn] = MFMA16(ah[fm], bh, acc2[fm][fn]);
          }
        }
      }
    }
  }
  // epilogue: write f32 partial to Pbuf via LDS for coalescing
  __syncthreads();
  float* ef = (float*)pool;   // [64][128] f32 = 32 KB (overlays sQ+sKV)
  for (int fm = 0; fm < 2; fm++) for (int fn = 0; fn < 2; fn++) {
    int c = w2n * 32 + fn * 16 + lr;
    for (int jj = 0; jj < 4; jj++) {
      int s = w2m * 32 + fm * 16 + lg * 4 + jj;
      ef[s * 128 + c] = acc2[fm][fn][jj];
    }
  }
  __syncthreads();
  float* po = Pbuf + ((size_t)((((b * 16 + i) * 8 + st) * 2) + dhalf)) * 8192;
  for (int idx = tid; idx < 2048; idx += 512)
    ((float4*)po)[idx] = ((const float4*)ef)[idx];
}

// ---- reduce the two d-half partials + U -> split attnout ----
__global__ void k_reduceB(const float* __restrict__ Pbuf, const float* __restrict__ U,
                          f16* __restrict__ aoh, f16* __restrict__ aol) {
  int blk = blockIdx.x;   // (b,i,st)
  int b = blk >> 7, i = (blk >> 3) & 15, st = blk & 7;
  int tid = threadIdx.x;
  __shared__ float sU[128];
  if (tid < 128) sU[tid] = U[((size_t)b * 16 + i) * 128 + tid];
  __syncthreads();
  const float4* p0 = (const float4*)(Pbuf + (size_t)blk * 2 * 8192);
  const float4* p1 = p0 + 2048;
  size_t obase = ((size_t)b * 8192 + i * 512 + st * 64) * 128;
  for (int idx = tid; idx < 2048; idx += 256) {
    float4 a = p0[idx], c = p1[idx];
    int cbase = (idx & 31) * 4;
    float vals[4] = {a.x + c.x, a.y + c.y, a.z + c.z, a.w + c.w};
    union { f16 v[4]; uint2 u; } rh, rl;
    for (int t = 0; t < 4; t++) {
      float v = vals[t] + sU[cbase + t];
      split2(v, rh.v[t], rl.v[t]);
    }
    *(uint2*)(aoh + obase + (size_t)idx * 4) = rh.u;
    *(uint2*)(aol + obase + (size_t)idx * 4) = rl.u;
  }
}

extern "C" void kernel_launch(void* const* d_in, const int* in_sizes, int n_in,
                              void* d_out, int out_size, void* d_ws, size_t ws_size,
                              hipStream_t stream) {
  const float* query     = (const float*)d_in[0];
  const float* key_value = (const float*)d_in[1];
  const float* Wq  = (const float*)d_in[2];
  const float* bq  = (const float*)d_in[3];
  const float* Wkv = (const float*)d_in[4];
  const float* bkv = (const float*)d_in[5];
  const float* Wo  = (const float*)d_in[6];
  const float* bo  = (const float*)d_in[7];
  float* out = (float*)d_out;

  char* ws = (char*)d_ws;
  size_t off = 0;
  auto alloc = [&](size_t bytes) -> char* {
    char* p = ws + off;
    off += (bytes + 255) & ~(size_t)255;
    return p;
  };
  const size_t SZH = (size_t)16384 * 128 * 2;   // one f16 array over all rows
  f16* qsh  = (f16*)alloc(SZH); f16* qsl  = (f16*)alloc(SZH);
  f16* kvsh = (f16*)alloc(SZH); f16* kvsl = (f16*)alloc(SZH);
  f16* qhp  = (f16*)alloc(SZH);   // q projected, single f16
  f16* khp  = (f16*)alloc(SZH);   // k projected, single f16
  f16* vT   = (f16*)alloc(SZH);   // v projected, transposed [b][c][l], single f16
  f16* aoh  = (f16*)alloc(SZH); f16* aol  = (f16*)alloc(SZH);
  f16* WqTh  = (f16*)alloc(32768); f16* WqTl  = (f16*)alloc(32768);
  f16* WkvTh = (f16*)alloc(65536); f16* WkvTl = (f16*)alloc(65536);
  f16* WoTh  = (f16*)alloc(32768); f16* WoTl  = (f16*)alloc(32768);
  float* Zb = (float*)alloc((size_t)2 * 16 * 16 * 512 * 4);
  float* Ub = (float*)alloc((size_t)2 * 16 * 128 * 4);
  if (off > ws_size) return;   // workspace too small: bail (output stays zero -> visible failure)
  // Pbuf (16.78 MB) aliases qsh/qsl/kvsh/kvsl — dead after the k_proj launches.
  float* Pbuf = (float*)ws;

  k_splitW<<<256, 256, 0, stream>>>(Wq, Wkv, Wo, WqTh, WqTl, WkvTh, WkvTl, WoTh, WoTl);
  k_split<<<2048, 256, 0, stream>>>((const float4*)query, (uint2*)qsh, (uint2*)qsl, 524288);
  k_split<<<2048, 256, 0, stream>>>((const float4*)key_value, (uint2*)kvsh, (uint2*)kvsl, 524288);
  // q projection
  k_proj<<<256, 512, 0, stream>>>(qsh, qsl, WqTh, WqTl, bq, qhp, 0);
  // k projection (first 128 channels of Wkv)
  k_proj<<<256, 512, 0, stream>>>(kvsh, kvsl, WkvTh, WkvTl, bkv, khp, 0);
  // v projection (second 128 channels), stored transposed [b][c][l]
  k_proj<<<256, 512, 0, stream>>>(kvsh, kvsl, WkvTh + 128 * 128, WkvTl + 128 * 128,
                                  bkv + 128, vT, 1);
  k_U<<<256, 256, 0, stream>>>(vT, Ub);
  k_passA<<<640, 512, 0, stream>>>(khp, qhp, Zb);
  k_passB<<<512, 512, 0, stream>>>(qhp, khp, vT, Zb, Pbuf);
  k_reduceB<<<256, 256, 0, stream>>>(Pbuf, Ub, aoh, aol);
  k_final<<<256, 512, 0, stream>>>(aoh, aol, WoTh, WoTl, bo, out);
}

// Round 5
// 144.781 us; speedup vs baseline: 2.1233x; 2.1233x over previous
//
#include <hip/hip_runtime.h>

typedef _Float16 f16;
typedef _Float16 half8 __attribute__((ext_vector_type(8)));
typedef float floatx4 __attribute__((ext_vector_type(4)));

#define MFMA16(a,b,c) __builtin_amdgcn_mfma_f32_16x16x32_f16((a),(b),(c),0,0,0)
// (1/sqrt(128)) * log2(e)
#define RSL2E 0.12751743f

__device__ __forceinline__ void split2(float x, f16 &h, f16 &l) {
  f16 hh = (f16)x;
  h = hh;
  l = (f16)(x - (float)hh);
}

// ---- LDS staging: rows of 64 halves (128B pitch), XOR-swizzled ----
__device__ __forceinline__ void stage_rows64(const f16* __restrict__ g, int gstride,
                                             f16* lds, int rows, int tid, int nthr) {
  int total = rows * 8;
  for (int idx = tid; idx < total; idx += nthr) {
    int row = idx >> 3, slot = idx & 7;
    float4 v = *(const float4*)(g + (size_t)row * gstride + slot * 8);
    int lofs = ((row << 7) + (slot << 4)) ^ ((row & 7) << 4);
    *(float4*)((char*)lds + lofs) = v;
  }
}
// rows of 128 halves (256B pitch), XOR-swizzled
__device__ __forceinline__ void stage_rows128(const f16* __restrict__ g, int gstride,
                                              f16* lds, int rows, int tid, int nthr) {
  int total = rows * 16;
  for (int idx = tid; idx < total; idx += nthr) {
    int row = idx >> 4, slot = idx & 15;
    float4 v = *(const float4*)(g + (size_t)row * gstride + slot * 8);
    int lofs = ((row << 8) + (slot << 4)) ^ ((row & 7) << 4);
    *(float4*)((char*)lds + lofs) = v;
  }
}
__device__ __forceinline__ half8 fragP128(const f16* lds, int row, int kofs) {
  int ofs = ((row << 7) + (kofs << 1)) ^ ((row & 7) << 4);
  return *(const half8*)((const char*)lds + ofs);
}
__device__ __forceinline__ half8 fragP256(const f16* lds, int row, int kofs) {
  int ofs = ((row << 8) + (kofs << 1)) ^ ((row & 7) << 4);
  return *(const half8*)((const char*)lds + ofs);
}

// ---- split fp32 -> (h,l) f16 pairs, elementwise ----
__global__ void k_split(const float4* __restrict__ in, uint2* __restrict__ outh,
                        uint2* __restrict__ outl, int n4) {
  int stride = gridDim.x * blockDim.x;
  for (int i = blockIdx.x * blockDim.x + threadIdx.x; i < n4; i += stride) {
    float4 v = in[i];
    union { f16 a[4]; uint2 u; } ph, pl;
    split2(v.x, ph.a[0], pl.a[0]);
    split2(v.y, ph.a[1], pl.a[1]);
    split2(v.z, ph.a[2], pl.a[2]);
    split2(v.w, ph.a[3], pl.a[3]);
    outh[i] = ph.u;
    outl[i] = pl.u;
  }
}

// ---- transpose + split the three weight matrices ----
__global__ void k_splitW(const float* __restrict__ Wq, const float* __restrict__ Wkv,
                         const float* __restrict__ Wo,
                         f16* WqTh, f16* WqTl, f16* WkvTh, f16* WkvTl,
                         f16* WoTh, f16* WoTl) {
  int idx = blockIdx.x * 256 + threadIdx.x;
  if (idx >= 65536) return;
  float v; f16 *ph, *pl; int dst;
  if (idx < 16384) {
    int n = idx >> 7, c = idx & 127;
    v = Wq[c * 128 + n]; ph = WqTh; pl = WqTl; dst = idx;
  } else if (idx < 49152) {
    int t = idx - 16384; int n = t >> 7, c = t & 127;
    v = Wkv[c * 256 + n]; ph = WkvTh; pl = WkvTl; dst = t;
  } else {
    int t = idx - 49152; int n = t >> 7, c = t & 127;
    v = Wo[c * 128 + n]; ph = WoTh; pl = WoTl; dst = t;
  }
  f16 h, l; split2(v, h, l);
  ph[dst] = h; pl[dst] = l;
}

// ---- split-f16 GEMM: out[64 rows][128 cols] = A[64][128] * BT[128][128]^T + bias ----
// Output is SINGLE f16 (rounded once). mode 0: row-major [l][c]; mode 1: transposed vT [b][c][l]
__global__ __launch_bounds__(512, 2)
void k_proj(const f16* __restrict__ Ah, const f16* __restrict__ Al,
            const f16* __restrict__ BTh, const f16* __restrict__ BTl,
            const float* __restrict__ bias,
            f16* __restrict__ out, int mode) {
  __shared__ f16 pool[24576];
  f16* sAh = pool;           // [64][64]
  f16* sAl = pool + 4096;
  f16* sBh = pool + 8192;    // [128][64]
  f16* sBl = pool + 16384;
  int tid = threadIdx.x, wave = tid >> 6, lane = tid & 63, lg = lane >> 4, lr = lane & 15;
  int wm = wave >> 2, wn = wave & 3;   // 2 x 4 waves, 32x32 wave tiles
  size_t rowbase = (size_t)blockIdx.x * 64;
  floatx4 zero = {0.f, 0.f, 0.f, 0.f};
  floatx4 acc[2][2] = {{zero, zero}, {zero, zero}};
  for (int cc = 0; cc < 128; cc += 64) {
    __syncthreads();
    stage_rows64(Ah + rowbase * 128 + cc, 128, sAh, 64, tid, 512);
    stage_rows64(Al + rowbase * 128 + cc, 128, sAl, 64, tid, 512);
    stage_rows64(BTh + cc, 128, sBh, 128, tid, 512);
    stage_rows64(BTl + cc, 128, sBl, 128, tid, 512);
    __syncthreads();
    for (int kc = 0; kc < 64; kc += 32) {
      half8 ah[2], al[2];
      for (int fm = 0; fm < 2; fm++) {
        ah[fm] = fragP128(sAh, wm * 32 + fm * 16 + lr, kc + lg * 8);
        al[fm] = fragP128(sAl, wm * 32 + fm * 16 + lr, kc + lg * 8);
      }
      for (int fn = 0; fn < 2; fn++) {
        half8 bh = fragP128(sBh, wn * 32 + fn * 16 + lr, kc + lg * 8);
        half8 bl = fragP128(sBl, wn * 32 + fn * 16 + lr, kc + lg * 8);
        for (int fm = 0; fm < 2; fm++) {
          acc[fm][fn] = MFMA16(ah[fm], bh, acc[fm][fn]);
          acc[fm][fn] = MFMA16(ah[fm], bl, acc[fm][fn]);
          acc[fm][fn] = MFMA16(al[fm], bh, acc[fm][fn]);
        }
      }
    }
  }
  __syncthreads();
  f16* e = pool;          // [64][136] padded, single
  for (int fm = 0; fm < 2; fm++) for (int fn = 0; fn < 2; fn++) {
    int n = wn * 32 + fn * 16 + lr;
    float bs = bias[n];
    for (int jj = 0; jj < 4; jj++) {
      int m = wm * 32 + fm * 16 + lg * 4 + jj;
      e[m * 136 + n] = (f16)(acc[fm][fn][jj] + bs);
    }
  }
  __syncthreads();
  if (mode == 0) {
    for (int idx = tid; idx < 1024; idx += 512) {
      int r = idx >> 4, sl = idx & 15;
      *(float4*)(out + (rowbase + r) * 128 + sl * 8) =
          *(const float4*)((const char*)e + r * 272 + sl * 16);
    }
  } else {
    size_t bidx = rowbase >> 13, lofs = rowbase & 8191;
    for (int idx = tid; idx < 1024; idx += 512) {
      int c = idx >> 3, sl = idx & 7;
      union { f16 a[8]; float4 v; } th;
      for (int t = 0; t < 8; t++) th.a[t] = e[(sl * 8 + t) * 136 + c];
      *(float4*)(out + (bidx * 128 + c) * 8192 + lofs + sl * 8) = th.v;
    }
  }
}

// ---- final projection: out fp32 = attnout(split) * WoT^T + bo ----
__global__ __launch_bounds__(512, 2)
void k_final(const f16* __restrict__ Ah, const f16* __restrict__ Al,
             const f16* __restrict__ BTh, const f16* __restrict__ BTl,
             const float* __restrict__ bias, float* __restrict__ out) {
  __shared__ f16 pool[24576];
  f16* sAh = pool;
  f16* sAl = pool + 4096;
  f16* sBh = pool + 8192;
  f16* sBl = pool + 16384;
  int tid = threadIdx.x, wave = tid >> 6, lane = tid & 63, lg = lane >> 4, lr = lane & 15;
  int wm = wave >> 2, wn = wave & 3;
  size_t rowbase = (size_t)blockIdx.x * 64;
  floatx4 zero = {0.f, 0.f, 0.f, 0.f};
  floatx4 acc[2][2] = {{zero, zero}, {zero, zero}};
  for (int cc = 0; cc < 128; cc += 64) {
    __syncthreads();
    stage_rows64(Ah + rowbase * 128 + cc, 128, sAh, 64, tid, 512);
    stage_rows64(Al + rowbase * 128 + cc, 128, sAl, 64, tid, 512);
    stage_rows64(BTh + cc, 128, sBh, 128, tid, 512);
    stage_rows64(BTl + cc, 128, sBl, 128, tid, 512);
    __syncthreads();
    for (int kc = 0; kc < 64; kc += 32) {
      half8 ah[2], al[2];
      for (int fm = 0; fm < 2; fm++) {
        ah[fm] = fragP128(sAh, wm * 32 + fm * 16 + lr, kc + lg * 8);
        al[fm] = fragP128(sAl, wm * 32 + fm * 16 + lr, kc + lg * 8);
      }
      for (int fn = 0; fn < 2; fn++) {
        half8 bh = fragP128(sBh, wn * 32 + fn * 16 + lr, kc + lg * 8);
        half8 bl = fragP128(sBl, wn * 32 + fn * 16 + lr, kc + lg * 8);
        for (int fm = 0; fm < 2; fm++) {
          acc[fm][fn] = MFMA16(ah[fm], bh, acc[fm][fn]);
          acc[fm][fn] = MFMA16(ah[fm], bl, acc[fm][fn]);
          acc[fm][fn] = MFMA16(al[fm], bh, acc[fm][fn]);
        }
      }
    }
  }
  __syncthreads();
  float* ef = (float*)pool;   // [64][132] padded fp32
  for (int fm = 0; fm < 2; fm++) for (int fn = 0; fn < 2; fn++) {
    int n = wn * 32 + fn * 16 + lr;
    float bs = bias[n];
    for (int jj = 0; jj < 4; jj++) {
      int m = wm * 32 + fm * 16 + lg * 4 + jj;
      ef[m * 132 + n] = acc[fm][fn][jj] + bs;
    }
  }
  __syncthreads();
  for (int idx = tid; idx < 2048; idx += 512) {
    int r = idx >> 5, sl = idx & 31;
    *(float4*)(out + (rowbase + r) * 128 + sl * 4) = *(const float4*)(ef + r * 132 + sl * 4);
  }
}

// ---- U[b][i][c] = (1/512) * sum over disallowed k-blocks of their column sums of v ----
__global__ void k_U(const f16* __restrict__ vT, float* __restrict__ U) {
  int b = blockIdx.x >> 7, c = blockIdx.x & 127;
  int tid = threadIdx.x;
  const f16* r = vT + ((size_t)b * 128 + c) * 8192;
  float s = 0.f;
  const float4* r4 = (const float4*)(r + tid * 32);
  for (int t = 0; t < 4; t++) {
    float4 v = r4[t];
    const f16* a = (const f16*)&v;
    for (int u = 0; u < 8; u++) s += (float)a[u];
  }
  __shared__ float part[256];
  __shared__ float bs[16];
  part[tid] = s;
  __syncthreads();
  if (tid < 16) {
    float t = 0.f;
    for (int u = 0; u < 16; u++) t += part[tid * 16 + u];
    bs[tid] = t;
  }
  __syncthreads();
  if (tid < 16) {
    int i = tid;
    float tot = 0.f;
    for (int j = 0; j < 16; j++) tot += bs[j];
    int j0 = i - 2 < 0 ? 0 : i - 2;
    int j1 = i + 2 > 15 ? 15 : i + 2;
    float win = 0.f;
    for (int j = j0; j <= j1; j++) win += bs[j];
    U[((size_t)b * 16 + i) * 128 + c] = (tot - win) * (1.0f / 512.0f);
  }
}

// ---- pass A: Z[b][i][j][d] = sum_s exp2(RSL2E * (k_d . q_s)), single f16 inputs ----
__global__ __launch_bounds__(512, 4)
void k_passA(const f16* __restrict__ kp, const f16* __restrict__ qp,
             float* __restrict__ Z) {
  int bid = blockIdx.x;
  int wg = (bid & 7) * 80 + (bid >> 3);     // XCD-aware bijective swizzle (640 = 8*80)
  int dchunk = wg & 3; int rest = wg >> 2;
  int slot = rest % 5; int rest2 = rest / 5;
  int i = rest2 & 15; int b = rest2 >> 4;
  int j = i - 2 + slot;
  if (j < 0 || j > 15) return;
  __shared__ f16 sK[16384], sQ[16384];  // 64 KiB -> 2 WG/CU
  int tid = threadIdx.x, wave = tid >> 6, lane = tid & 63, lg = lane >> 4, lr = lane & 15;
  int wm = wave >> 1, wn = wave & 1;   // 4 x 2 waves; wave tile 32(d) x 64(s)
  size_t krow = (size_t)b * 8192 + j * 512 + dchunk * 128;
  stage_rows128(kp + krow * 128, 128, sK, 128, tid, 512);
  float zp[2][4] = {{0.f,0.f,0.f,0.f},{0.f,0.f,0.f,0.f}};
  floatx4 zero = {0.f, 0.f, 0.f, 0.f};
  for (int sc = 0; sc < 4; sc++) {
    __syncthreads();
    size_t qrow = (size_t)b * 8192 + i * 512 + sc * 128;
    stage_rows128(qp + qrow * 128, 128, sQ, 128, tid, 512);
    __syncthreads();
    floatx4 acc[2][4] = {{zero,zero,zero,zero},{zero,zero,zero,zero}};
    for (int kc = 0; kc < 128; kc += 32) {
      half8 ah[2];
      for (int fm = 0; fm < 2; fm++)
        ah[fm] = fragP256(sK, wm * 32 + fm * 16 + lr, kc + lg * 8);
      for (int fn = 0; fn < 4; fn++) {
        half8 bh = fragP256(sQ, wn * 64 + fn * 16 + lr, kc + lg * 8);
        for (int fm = 0; fm < 2; fm++)
          acc[fm][fn] = MFMA16(ah[fm], bh, acc[fm][fn]);
      }
    }
    for (int fm = 0; fm < 2; fm++) for (int fn = 0; fn < 4; fn++)
      for (int jj = 0; jj < 4; jj++)
        zp[fm][jj] += exp2f(acc[fm][fn][jj] * RSL2E);
  }
  // in-wave butterfly over lr (16 s-columns)
  for (int off = 1; off < 16; off <<= 1)
    for (int fm = 0; fm < 2; fm++) for (int jj = 0; jj < 4; jj++)
      zp[fm][jj] += __shfl_xor(zp[fm][jj], off, 64);
  // cross-wave combine of the two wn halves via LDS
  __syncthreads();
  float* sred = (float*)sQ;      // 256 floats
  if (lr == 0) {
    for (int fm = 0; fm < 2; fm++) for (int jj = 0; jj < 4; jj++) {
      int d = wm * 32 + fm * 16 + lg * 4 + jj;
      sred[wn * 128 + d] = zp[fm][jj];
    }
  }
  __syncthreads();
  if (tid < 128) {
    size_t zb = (((size_t)(b * 16 + i) * 16 + j) * 512) + dchunk * 128;
    Z[zb + tid] = sred[tid] + sred[128 + tid];
  }
}

// ---- pass B: per (b, i, s-tile of 64, d-half of 256): partial PV into Pbuf (f32) ----
// single-f16 operands; 40 KB LDS; launch_bounds(512,4) => VGPR cap 128, NO SPILL (R4 lesson)
__global__ __launch_bounds__(512, 4)
void k_passB(const f16* __restrict__ qp, const f16* __restrict__ kp,
             const f16* __restrict__ vT,
             const float* __restrict__ Z, float* __restrict__ Pbuf) {
  int bid = blockIdx.x;
  int wg = ((bid & 7) << 6) | (bid >> 3);   // XCD-aware bijective swizzle (512 = 8*64)
  int dhalf = wg & 1, st = (wg >> 1) & 7, i = (wg >> 4) & 15, b = wg >> 8;
  __shared__ __align__(16) char pool[40960];
  f16* sQ  = (f16*)pool;             // [64 s][128 c], 256B pitch, 16 KB
  f16* sKV = (f16*)(pool + 16384);   // [128][64], 128B pitch, 16 KB (K halves / vT tiles)
  f16* sE  = (f16*)(pool + 32768);   // [64 s][64 d], 128B pitch, 8 KB
  int tid = threadIdx.x, wave = tid >> 6, lane = tid & 63, lg = lane >> 4, lr = lane & 15;
  int w1m = wave >> 1, w1n = wave & 1;    // GEMM1: 4(d) x 2(s)
  int w2m = wave >> 2, w2n = wave & 3;    // GEMM2: 2(s) x 4(c)
  // this thread's K-stage duty (rows krr and krr+64, 16B slot ksl)
  int krr = tid >> 3, ksl = tid & 7;
  int lofsA = ((krr << 7) + (ksl << 4)) ^ ((krr & 7) << 4);
  int lofsB = (((krr + 64) << 7) + (ksl << 4)) ^ ((krr & 7) << 4);
  size_t qrow = (size_t)b * 8192 + i * 512 + st * 64;
  stage_rows128(qp + qrow * 128, 128, sQ, 64, tid, 512);
  floatx4 zero = {0.f, 0.f, 0.f, 0.f};
  floatx4 acc2[2][2] = {{zero, zero}, {zero, zero}};
  for (int slot = 0; slot < 5; slot++) {
    int j = i - 2 + slot;
    if (j < 0 || j > 15) continue;
    for (int dc = 0; dc < 2; dc++) {
      int dchunk = dhalf * 2 + dc;
      const f16* kb = kp + ((size_t)b * 8192 + j * 512 + dchunk * 128) * 128;
      // T14: issue cc=0 loads BEFORE the barrier
      float4 p0a = *(const float4*)(kb + krr * 128 + ksl * 8);
      float4 p0b = *(const float4*)(kb + (krr + 64) * 128 + ksl * 8);
      floatx4 acc1[2][2] = {{zero, zero}, {zero, zero}};
      __syncthreads();                       // prev readers of sKV done
      *(float4*)((char*)sKV + lofsA) = p0a;
      *(float4*)((char*)sKV + lofsB) = p0b;
      // prefetch cc=64 (lands during GEMM1(cc=0))
      float4 p1a = *(const float4*)(kb + krr * 128 + 64 + ksl * 8);
      float4 p1b = *(const float4*)(kb + (krr + 64) * 128 + 64 + ksl * 8);
      __syncthreads();
      for (int kc = 0; kc < 64; kc += 32) {  // GEMM1 over cc=0 half
        half8 ah[2];
        for (int fm = 0; fm < 2; fm++)
          ah[fm] = fragP128(sKV, w1m * 32 + fm * 16 + lr, kc + lg * 8);
        for (int fn = 0; fn < 2; fn++) {
          half8 bh = fragP256(sQ, w1n * 32 + fn * 16 + lr, kc + lg * 8);
          for (int fm = 0; fm < 2; fm++)
            acc1[fm][fn] = MFMA16(ah[fm], bh, acc1[fm][fn]);
        }
      }
      __syncthreads();
      *(float4*)((char*)sKV + lofsA) = p1a;
      *(float4*)((char*)sKV + lofsB) = p1b;
      __syncthreads();
      for (int kc = 0; kc < 64; kc += 32) {  // GEMM1 over cc=64 half
        half8 ah[2];
        for (int fm = 0; fm < 2; fm++)
          ah[fm] = fragP128(sKV, w1m * 32 + fm * 16 + lr, kc + lg * 8);
        for (int fn = 0; fn < 2; fn++) {
          half8 bh = fragP256(sQ, w1n * 32 + fn * 16 + lr, 64 + kc + lg * 8);
          for (int fm = 0; fm < 2; fm++)
            acc1[fm][fn] = MFMA16(ah[fm], bh, acc1[fm][fn]);
        }
      }
      float rz[2][4];
      {
        size_t zb = (((size_t)(b * 16 + i) * 16 + j) * 512) + dchunk * 128;
        for (int fm = 0; fm < 2; fm++) for (int jj = 0; jj < 4; jj++)
          rz[fm][jj] = 1.0f / Z[zb + w1m * 32 + fm * 16 + lg * 4 + jj];
      }
      for (int dsub = 0; dsub < 2; dsub++) {
        __syncthreads();   // prev GEMM2 done with E and KV buffers
        if ((w1m >> 1) == dsub) {
          // this half's waves write E' = exp(S)/Z (single f16)
          for (int fm = 0; fm < 2; fm++) for (int fn = 0; fn < 2; fn++)
            for (int jj = 0; jj < 4; jj++) {
              int dl = w1m * 32 + fm * 16 + lg * 4 + jj;
              int ds = dl - dsub * 64;
              int s = w1n * 32 + fn * 16 + lr;
              float e = exp2f(acc1[fm][fn][jj] * RSL2E) * rz[fm][jj];
              int ofs = ((s << 7) + (ds << 1)) ^ ((s & 7) << 4);
              *(f16*)((char*)sE + ofs) = (f16)e;
            }
        } else {
          // other 4 waves stage vT tile [128 c][64 d]
          int tt = (wave >= 4) ? (tid - 256) : tid;
          size_t vcol = (size_t)j * 512 + dchunk * 128 + dsub * 64;
          const f16* gv = vT + (size_t)b * 128 * 8192 + vcol;
          for (int idx = tt; idx < 1024; idx += 256) {
            int row = idx >> 3, sl = idx & 7;
            int lofs = ((row << 7) + (sl << 4)) ^ ((row & 7) << 4);
            *(float4*)((char*)sKV + lofs) = *(const float4*)(gv + (size_t)row * 8192 + sl * 8);
          }
        }
        __syncthreads();
        for (int kc = 0; kc < 64; kc += 32) {
          half8 ah[2];
          for (int fm = 0; fm < 2; fm++)
            ah[fm] = fragP128(sE, w2m * 32 + fm * 16 + lr, kc + lg * 8);
          for (int fn = 0; fn < 2; fn++) {
            half8 bh = fragP128(sKV, w2n * 32 + fn * 16 + lr, kc + lg * 8);
            for (int fm = 0; fm < 2; fm++)
              acc2[fm][fn] = MFMA16(ah[fm], bh, acc2[fm][fn]);
          }
        }
      }
    }
  }
  // epilogue: write f32 partial to Pbuf via LDS for coalescing
  __syncthreads();
  float* ef = (float*)pool;   // [64][128] f32 = 32 KB (overlays sQ+sKV)
  for (int fm = 0; fm < 2; fm++) for (int fn = 0; fn < 2; fn++) {
    int c = w2n * 32 + fn * 16 + lr;
    for (int jj = 0; jj < 4; jj++) {
      int s = w2m * 32 + fm * 16 + lg * 4 + jj;
      ef[s * 128 + c] = acc2[fm][fn][jj];
    }
  }
  __syncthreads();
  float* po = Pbuf + ((size_t)((((b * 16 + i) * 8 + st) * 2) + dhalf)) * 8192;
  for (int idx = tid; idx < 2048; idx += 512)
    ((float4*)po)[idx] = ((const float4*)ef)[idx];
}

// ---- reduce the two d-half partials + U -> split attnout ----
__global__ void k_reduceB(const float* __restrict__ Pbuf, const float* __restrict__ U,
                          f16* __restrict__ aoh, f16* __restrict__ aol) {
  int blk = blockIdx.x;   // (b,i,st)
  int b = blk >> 7, i = (blk >> 3) & 15, st = blk & 7;
  int tid = threadIdx.x;
  __shared__ float sU[128];
  if (tid < 128) sU[tid] = U[((size_t)b * 16 + i) * 128 + tid];
  __syncthreads();
  const float4* p0 = (const float4*)(Pbuf + (size_t)blk * 2 * 8192);
  const float4* p1 = p0 + 2048;
  size_t obase = ((size_t)b * 8192 + i * 512 + st * 64) * 128;
  for (int idx = tid; idx < 2048; idx += 256) {
    float4 a = p0[idx], c = p1[idx];
    int cbase = (idx & 31) * 4;
    float vals[4] = {a.x + c.x, a.y + c.y, a.z + c.z, a.w + c.w};
    union { f16 v[4]; uint2 u; } rh, rl;
    for (int t = 0; t < 4; t++) {
      float v = vals[t] + sU[cbase + t];
      split2(v, rh.v[t], rl.v[t]);
    }
    *(uint2*)(aoh + obase + (size_t)idx * 4) = rh.u;
    *(uint2*)(aol + obase + (size_t)idx * 4) = rl.u;
  }
}

extern "C" void kernel_launch(void* const* d_in, const int* in_sizes, int n_in,
                              void* d_out, int out_size, void* d_ws, size_t ws_size,
                              hipStream_t stream) {
  const float* query     = (const float*)d_in[0];
  const float* key_value = (const float*)d_in[1];
  const float* Wq  = (const float*)d_in[2];
  const float* bq  = (const float*)d_in[3];
  const float* Wkv = (const float*)d_in[4];
  const float* bkv = (const float*)d_in[5];
  const float* Wo  = (const float*)d_in[6];
  const float* bo  = (const float*)d_in[7];
  float* out = (float*)d_out;

  char* ws = (char*)d_ws;
  size_t off = 0;
  auto alloc = [&](size_t bytes) -> char* {
    char* p = ws + off;
    off += (bytes + 255) & ~(size_t)255;
    return p;
  };
  const size_t SZH = (size_t)16384 * 128 * 2;   // one f16 array over all rows
  f16* qsh  = (f16*)alloc(SZH); f16* qsl  = (f16*)alloc(SZH);
  f16* kvsh = (f16*)alloc(SZH); f16* kvsl = (f16*)alloc(SZH);
  f16* qhp  = (f16*)alloc(SZH);   // q projected, single f16
  f16* khp  = (f16*)alloc(SZH);   // k projected, single f16
  f16* vT   = (f16*)alloc(SZH);   // v projected, transposed [b][c][l], single f16
  f16* aoh  = (f16*)alloc(SZH); f16* aol  = (f16*)alloc(SZH);
  f16* WqTh  = (f16*)alloc(32768); f16* WqTl  = (f16*)alloc(32768);
  f16* WkvTh = (f16*)alloc(65536); f16* WkvTl = (f16*)alloc(65536);
  f16* WoTh  = (f16*)alloc(32768); f16* WoTl  = (f16*)alloc(32768);
  float* Zb = (float*)alloc((size_t)2 * 16 * 16 * 512 * 4);
  float* Ub = (float*)alloc((size_t)2 * 16 * 128 * 4);
  if (off > ws_size) return;   // workspace too small: bail (output stays zero -> visible failure)
  // Pbuf (16.78 MB) aliases qsh/qsl/kvsh/kvsl — dead after the k_proj launches.
  float* Pbuf = (float*)ws;

  k_splitW<<<256, 256, 0, stream>>>(Wq, Wkv, Wo, WqTh, WqTl, WkvTh, WkvTl, WoTh, WoTl);
  k_split<<<2048, 256, 0, stream>>>((const float4*)query, (uint2*)qsh, (uint2*)qsl, 524288);
  k_split<<<2048, 256, 0, stream>>>((const float4*)key_value, (uint2*)kvsh, (uint2*)kvsl, 524288);
  // q projection
  k_proj<<<256, 512, 0, stream>>>(qsh, qsl, WqTh, WqTl, bq, qhp, 0);
  // k projection (first 128 channels of Wkv)
  k_proj<<<256, 512, 0, stream>>>(kvsh, kvsl, WkvTh, WkvTl, bkv, khp, 0);
  // v projection (second 128 channels), stored transposed [b][c][l]
  k_proj<<<256, 512, 0, stream>>>(kvsh, kvsl, WkvTh + 128 * 128, WkvTl + 128 * 128,
                                  bkv + 128, vT, 1);
  k_U<<<256, 256, 0, stream>>>(vT, Ub);
  k_passA<<<640, 512, 0, stream>>>(khp, qhp, Zb);
  k_passB<<<512, 512, 0, stream>>>(qhp, khp, vT, Zb, Pbuf);
  k_reduceB<<<256, 256, 0, stream>>>(Pbuf, Ub, aoh, aol);
  k_final<<<256, 512, 0, stream>>>(aoh, aol, WoTh, WoTl, bo, out);
}